// Round 6
// baseline (1228.158 us; speedup 1.0000x reference)
//
#include <hip/hip_runtime.h>
#include <math.h>

#define NN 50000
#define NE 800000
#define D 64
#define RPW 8   // rows owned per wave

typedef __attribute__((ext_vector_type(8))) short short8;
typedef __attribute__((ext_vector_type(4))) float f32x4;

__device__ __forceinline__ float silu_f(float x) { return x / (1.0f + __expf(-x)); }

// v_cvt_pk_bf16_f32: D[15:0]=bf16(S0), D[31:16]=bf16(S1), round-to-nearest-even.
__device__ __forceinline__ unsigned int pack2(float a, float b) {
  unsigned int r;
  asm("v_cvt_pk_bf16_f32 %0, %1, %2" : "=v"(r) : "v"(a), "v"(b));
  return r;
}
__device__ __forceinline__ short8 pack_frag(f32x4 a, f32x4 b) {
  union { unsigned int u[4]; short8 s; } r;
  r.u[0] = pack2(a[0], a[1]);
  r.u[1] = pack2(a[2], a[3]);
  r.u[2] = pack2(b[0], b[1]);
  r.u[3] = pack2(b[2], b[3]);
  return r.s;
}

// ---------------------------------------------------------------------------
// prep_all (fused): weight frags w/ INLINE fold, bprime, and row histogram.
// Launched at NE threads (3125 blocks) so the hist rides in this dispatch.
// Frag layout: 0..7 eg_w1 | 8..55 H1W fold | 56..71 mg_w2 | 72..79 ng_w1 |
//              80..87 up_w.  frag elem(L,j) = W[ks*32+(L>>4)*8+j][nt*16+(L&15)]
// ---------------------------------------------------------------------------
__global__ void prep_all(const float* __restrict__ eg_w1,
                         const float* __restrict__ mg_w2,
                         const float* __restrict__ ng_w1,
                         const float* __restrict__ up_w,
                         const float* __restrict__ ng_w2,
                         const float* __restrict__ eg_w2,
                         const float* __restrict__ mg_w1,
                         const float* __restrict__ mg_b1,
                         const float* __restrict__ ng_b2,
                         const float* __restrict__ eg_b2,
                         const int* __restrict__ ei,
                         unsigned short* __restrict__ outWF,
                         float* __restrict__ bprime,
                         int* __restrict__ cnt) {
  int t = blockIdx.x * 256 + threadIdx.x;
  if (t < 88 * 64) {
    int frag = t >> 6, L = t & 63;
    unsigned int p[4];
    if (frag >= 8 && frag < 56) {
      // folded H1W: Wsrc = A_src @ mg_w1[src*64 : src*64+64], computed inline.
      int lf = frag - 8, mt = lf / 6, s2 = lf % 6, src = s2 >> 1, ks = s2 & 1;
      const float* A = (src == 2) ? eg_w2 : ng_w2;
      const float* M = mg_w1 + (size_t)src * 64 * 128;
      int kb = ks * 32 + (L >> 4) * 8;
      int nc = mt * 16 + (L & 15);
#pragma unroll
      for (int jj = 0; jj < 4; ++jj) {
        float a = 0.f, b = 0.f;
        for (int n = 0; n < 64; ++n) {
          float m = M[(size_t)n * 128 + nc];
          a += A[(kb + 2 * jj) * 64 + n] * m;
          b += A[(kb + 2 * jj + 1) * 64 + n] * m;
        }
        p[jj] = pack2(a, b);
      }
    } else {
      const float* W; int N, nt, ks;
      if (frag < 8)       { W = eg_w1; N = 64; nt = frag >> 1; ks = frag & 1; }
      else if (frag < 72) { int lf = frag - 56; W = mg_w2; N = 64; nt = lf >> 2; ks = lf & 3; }
      else if (frag < 80) { int lf = frag - 72; W = ng_w1; N = 64; nt = lf >> 1; ks = lf & 1; }
      else                { int lf = frag - 80; W = up_w;  N = 64; nt = lf >> 1; ks = lf & 1; }
      int kb = ks * 32 + (L >> 4) * 8;
      int nc = nt * 16 + (L & 15);
#pragma unroll
      for (int jj = 0; jj < 4; ++jj) {
        float a = W[(size_t)(kb + 2 * jj) * N + nc];
        float b = W[(size_t)(kb + 2 * jj + 1) * N + nc];
        p[jj] = pack2(a, b);
      }
    }
    *(uint4*)(outWF + (size_t)frag * 512 + L * 8) = make_uint4(p[0], p[1], p[2], p[3]);
  } else if (t < 88 * 64 + 128) {
    int m = t - 88 * 64;
    float acc = mg_b1[m];
    for (int n = 0; n < 64; ++n)
      acc += ng_b2[n] * (mg_w1[(size_t)n * 128 + m] + mg_w1[(size_t)(64 + n) * 128 + m]) +
             eg_b2[n] * mg_w1[(size_t)(128 + n) * 128 + m];
    bprime[m] = acc;
  }
  if (t < NE) atomicAdd(&cnt[ei[t]], 1);
}

// ---------------------------------------------------------------------------
// scan: exclusive prefix over cnt -> row_start, cursor. Single block.
// ---------------------------------------------------------------------------
#define SCH ((NN + 1023) / 1024)
__global__ __launch_bounds__(1024) void scan_k(const int* __restrict__ cnt,
                                               int* __restrict__ row_start,
                                               int* __restrict__ cursor) {
  __shared__ int wsum[16];
  int t = threadIdx.x, lane = t & 63, w = t >> 6;
  int base = t * SCH;
  int s = 0;
  for (int i = 0; i < SCH; ++i) {
    int b = base + i;
    if (b < NN) s += cnt[b];
  }
  int v = s;
#pragma unroll
  for (int off = 1; off < 64; off <<= 1) {
    int y = __shfl_up(v, off, 64);
    if (lane >= off) v += y;
  }
  if (lane == 63) wsum[w] = v;
  __syncthreads();
  int woff = 0;
  for (int i = 0; i < w; ++i) woff += wsum[i];
  int run = woff + v - s;
  for (int i = 0; i < SCH; ++i) {
    int b = base + i;
    if (b < NN) {
      row_start[b] = run;
      cursor[b] = run;
      run += cnt[b];
    }
  }
  if (t == 1023) row_start[NN] = run;
}

// ---------------------------------------------------------------------------
// node_pre: h_ng = s @ ng_w1[0:64] + b1 (MFMA), zero s_agg/v_agg, THEN a
// grid-strided tail that builds perm + sorted-order rowS/colS/evuS (fused
// to avoid an extra ~50us dispatch).
// ---------------------------------------------------------------------------
__global__ __launch_bounds__(256, 4) void node_pre(
    const float* __restrict__ s, const float* __restrict__ ng_b1,
    const unsigned short* __restrict__ WF, float* __restrict__ h_ng,
    float* __restrict__ s_agg, float* __restrict__ v_agg,
    const int* __restrict__ ei, const float* __restrict__ evu,
    int* __restrict__ cursor, int* __restrict__ perm,
    int* __restrict__ rowS, int* __restrict__ colS, float* __restrict__ evuS) {
  __shared__ __align__(16) char sm[4 * 8704];
  int tid = threadIdx.x, w = tid >> 6, lane = tid & 63;
  int l15 = lane & 15, q = lane >> 4, fb = q * 8;
  char* my = sm + w * 8704;
  int nb = (blockIdx.x * 4 + w) * 32;

  if (nb < NN) {
    short8 Bs[2][2];
#pragma unroll
    for (int h = 0; h < 2; ++h)
#pragma unroll
      for (int kt = 0; kt < 2; ++kt) {
        int n = nb + h * 16 + l15; if (n >= NN) n = NN - 1;
        f32x4 x0 = *(const f32x4*)(s + (size_t)n * D + kt * 32 + fb);
        f32x4 x1 = *(const f32x4*)(s + (size_t)n * D + kt * 32 + fb + 4);
        Bs[h][kt] = pack_frag(x0, x1);
      }
    short8 F[4][2]; f32x4 bb[4];
#pragma unroll
    for (int mt = 0; mt < 4; ++mt) {
      F[mt][0] = *(const short8*)(WF + (size_t)(72 + mt * 2 + 0) * 512 + lane * 8);
      F[mt][1] = *(const short8*)(WF + (size_t)(72 + mt * 2 + 1) * 512 + lane * 8);
      bb[mt] = *(const f32x4*)(ng_b1 + mt * 16 + 4 * q);
    }
#pragma unroll
    for (int h = 0; h < 2; ++h)
#pragma unroll
      for (int mt = 0; mt < 4; ++mt) {
        f32x4 acc = {0.f, 0.f, 0.f, 0.f};
        acc = __builtin_amdgcn_mfma_f32_16x16x32_bf16(F[mt][0], Bs[h][0], acc, 0, 0, 0);
        acc = __builtin_amdgcn_mfma_f32_16x16x32_bf16(F[mt][1], Bs[h][1], acc, 0, 0, 0);
        acc[0] += bb[mt][0]; acc[1] += bb[mt][1]; acc[2] += bb[mt][2]; acc[3] += bb[mt][3];
        *(f32x4*)(my + (((h * 16 + l15) * 68 + mt * 16 + 4 * q) << 2)) = acc;
      }
#pragma unroll
    for (int h = 0; h < 2; ++h)
#pragma unroll
      for (int e = 0; e < 16; ++e) {
        int n = nb + h * 16 + e;
        if (n < NN) {
          float val = *(const float*)(my + (((h * 16 + e) * 68 + lane) << 2));
          h_ng[(size_t)n * D + lane] = val;
          s_agg[(size_t)n * D + lane] = 0.f;
        }
      }
#pragma unroll
    for (int h = 0; h < 2; ++h) {
      int n = nb + h * 16 + l15;
      if (q < 3 && n < NN) v_agg[(size_t)n * 3 + q] = 0.f;
    }
  }

  // ---- fused perm + pre-gather build (sorted edge order)
  int gtid = blockIdx.x * 256 + threadIdx.x;
  int stride = gridDim.x * 256;
  for (int e = gtid; e < NE; e += stride) {
    int r = ei[e], c = ei[NE + e];
    int slot = atomicAdd(&cursor[r], 1);
    perm[slot] = e;
    rowS[slot] = r;
    colS[slot] = c;
    evuS[(size_t)slot * 3 + 0] = evu[(size_t)e * 3 + 0];
    evuS[(size_t)slot * 3 + 1] = evu[(size_t)e * 3 + 1];
    evuS[(size_t)slot * 3 + 2] = evu[(size_t)e * 3 + 2];
  }
}

// ---------------------------------------------------------------------------
// edge_mfma: ROW-OWNER folded pipeline. Each wave exclusively owns RPW=8
// consecutive rows and iterates their CSR slot span in 32-edge batches.
// s_agg aggregation = f32 register carry, flushed on row change with a PLAIN
// STORE (no atomics at all on s_agg; each row written exactly once).
// rowS/colS/evuS are read as coalesced sorted streams. LSTR=68 (mod32=4),
// 34.8KB/block -> 4 blocks/CU.
// ---------------------------------------------------------------------------
#define LSTR 68
#define LDSW (32 * LSTR * 4)

__global__ __launch_bounds__(256, 4) void edge_mfma(
    const float* __restrict__ v,
    const float* __restrict__ edge_attr,
    const float* __restrict__ ng_w1, const float* __restrict__ eg_w1,
    const float* __restrict__ eg_b1, const float* __restrict__ bprime,
    const float* __restrict__ mg_b2,
    const float* __restrict__ pe_w, const float* __restrict__ pe_b,
    const float* __restrict__ h_ng,
    const unsigned short* __restrict__ WF,
    const int* __restrict__ perm, const int* __restrict__ rowS,
    const int* __restrict__ colS, const float* __restrict__ evuS,
    const int* __restrict__ row_start,
    float* __restrict__ s_agg, float* __restrict__ v_agg) {
  __shared__ __align__(16) char sm[4 * LDSW];
  int tid = threadIdx.x, w = tid >> 6, lane = tid & 63;
  int l15 = lane & 15, q = lane >> 4, fb = q * 8;
  char* my = sm + w * LDSW;

  int wid = blockIdx.x * 4 + w;
  int r0 = wid * RPW;
  if (r0 >= NN) return;
  int r1 = r0 + RPW; if (r1 > NN) r1 = NN;
  int sBeg = row_start[r0], sEnd = row_start[r1];

  // invariant: last row of ng_w1 (residual column weight)
  f32x4 w1l[2][2];
#pragma unroll
  for (int kt = 0; kt < 2; ++kt) {
    w1l[kt][0] = *(const f32x4*)(ng_w1 + 64 * 64 + kt * 32 + fb);
    w1l[kt][1] = *(const f32x4*)(ng_w1 + 64 * 64 + kt * 32 + fb + 4);
  }

  int prevRow = -1;
  float accR = 0.f;

  for (int base = sBeg; base < sEnd; base += 32) {
    int cntA = sEnd - base; if (cntA > 32) cntA = 32;

    // ---- per-edge scalars from SORTED streams
    int pe[2], rown[2], coln[2];
    float rij[2], rji[2], uu0[2], uu1[2], uu2[2], cmag[2];
    bool act[2];
#pragma unroll
    for (int h = 0; h < 2; ++h) {
      int sl = base + h * 16 + l15;
      act[h] = (sl < sEnd);
      if (sl >= sEnd) sl = sEnd - 1;
      int e = perm[sl];
      pe[h] = e;
      int r = rowS[sl], c = colS[sl];
      rown[h] = r; coln[h] = c;
      float u0 = evuS[(size_t)sl * 3 + 0];
      float u1 = evuS[(size_t)sl * 3 + 1];
      float u2 = evuS[(size_t)sl * 3 + 2];
      uu0[h] = u0; uu1[h] = u1; uu2[h] = u2;
      float vi0 = v[r * 3 + 0], vi1 = v[r * 3 + 1], vi2 = v[r * 3 + 2];
      float vj0 = v[c * 3 + 0], vj1 = v[c * 3 + 1], vj2 = v[c * 3 + 2];
      rij[h] = 1.f - (vi0 * u0 + vi1 * u1 + vi2 * u2);
      rji[h] = 1.f + (vj0 * u0 + vj1 * u1 + vj2 * u2);
      float cx = vi1 * vj2 - vi2 * vj1;
      float cy = vi2 * vj0 - vi0 * vj2;
      float cz = vi0 * vj1 - vi1 * vj0;
      cmag[h] = sqrtf(cx * cx + cy * cy + cz * cz);
    }

    // ---- stage B-frags: a_i, a_j (silu of hoisted layer + res*w1last), Xe
    short8 Bai[2][2], Baj[2][2], Bxe[2][2];
#pragma unroll
    for (int h = 0; h < 2; ++h)
#pragma unroll
      for (int kt = 0; kt < 2; ++kt) {
        const float* pr = h_ng + (size_t)rown[h] * D + kt * 32 + fb;
        const float* pc = h_ng + (size_t)coln[h] * D + kt * 32 + fb;
        const float* px = edge_attr + (size_t)pe[h] * D + kt * 32 + fb;
        f32x4 a0 = *(const f32x4*)pr, a1 = *(const f32x4*)(pr + 4);
        f32x4 b0 = *(const f32x4*)pc, b1 = *(const f32x4*)(pc + 4);
        f32x4 x0 = *(const f32x4*)px, x1 = *(const f32x4*)(px + 4);
        f32x4 si0, si1, sj0, sj1;
#pragma unroll
        for (int c2 = 0; c2 < 4; ++c2) {
          si0[c2] = silu_f(a0[c2] + rij[h] * w1l[kt][0][c2]);
          si1[c2] = silu_f(a1[c2] + rij[h] * w1l[kt][1][c2]);
          sj0[c2] = silu_f(b0[c2] + rji[h] * w1l[kt][0][c2]);
          sj1[c2] = silu_f(b1[c2] + rji[h] * w1l[kt][1][c2]);
        }
        Bai[h][kt] = pack_frag(si0, si1);
        Baj[h][kt] = pack_frag(sj0, sj1);
        Bxe[h][kt] = pack_frag(x0, x1);
      }

    // ---- ae = silu(Xe @ eg_w1 + b + cmag*w_last)  -> LDS fdw 0..31
    {
      short8 F[4][2]; f32x4 bb[4], el[4];
#pragma unroll
      for (int mt = 0; mt < 4; ++mt) {
        F[mt][0] = *(const short8*)(WF + (size_t)(0 + mt * 2 + 0) * 512 + lane * 8);
        F[mt][1] = *(const short8*)(WF + (size_t)(0 + mt * 2 + 1) * 512 + lane * 8);
        bb[mt] = *(const f32x4*)(eg_b1 + mt * 16 + 4 * q);
        el[mt] = *(const f32x4*)(eg_w1 + 64 * 64 + mt * 16 + 4 * q);
      }
#pragma unroll
      for (int h = 0; h < 2; ++h)
#pragma unroll
        for (int mt = 0; mt < 4; ++mt) {
          f32x4 acc = {0.f, 0.f, 0.f, 0.f};
          acc = __builtin_amdgcn_mfma_f32_16x16x32_bf16(F[mt][0], Bxe[h][0], acc, 0, 0, 0);
          acc = __builtin_amdgcn_mfma_f32_16x16x32_bf16(F[mt][1], Bxe[h][1], acc, 0, 0, 0);
          float t0 = silu_f(acc[0] + bb[mt][0] + cmag[h] * el[mt][0]);
          float t1 = silu_f(acc[1] + bb[mt][1] + cmag[h] * el[mt][1]);
          float t2 = silu_f(acc[2] + bb[mt][2] + cmag[h] * el[mt][2]);
          float t3 = silu_f(acc[3] + bb[mt][3] + cmag[h] * el[mt][3]);
          uint2 p; p.x = pack2(t0, t1); p.y = pack2(t2, t3);
          *(uint2*)(my + (((h * 16 + l15) * LSTR + mt * 8 + 2 * q) << 2)) = p;
        }
    }

    // ---- read ae B-frags into regs (before h1 overwrites fdw 0..31)
    short8 Bae[2][2];
#pragma unroll
    for (int h = 0; h < 2; ++h)
#pragma unroll
      for (int kt = 0; kt < 2; ++kt)
        Bae[h][kt] = *(const short8*)(my + (((h * 16 + l15) * LSTR + 16 * kt + 4 * q) << 2));

    // ---- h1 = silu(ai@Wi + aj@Wj + ae@We + b'): write fdw 0..63
#pragma unroll
    for (int mt = 0; mt < 8; ++mt) {
      short8 F[6];
#pragma unroll
      for (int s2 = 0; s2 < 6; ++s2)
        F[s2] = *(const short8*)(WF + (size_t)(8 + mt * 6 + s2) * 512 + lane * 8);
      f32x4 bb = *(const f32x4*)(bprime + mt * 16 + 4 * q);
#pragma unroll
      for (int h = 0; h < 2; ++h) {
        f32x4 acc = {0.f, 0.f, 0.f, 0.f};
        acc = __builtin_amdgcn_mfma_f32_16x16x32_bf16(F[0], Bai[h][0], acc, 0, 0, 0);
        acc = __builtin_amdgcn_mfma_f32_16x16x32_bf16(F[1], Bai[h][1], acc, 0, 0, 0);
        acc = __builtin_amdgcn_mfma_f32_16x16x32_bf16(F[2], Baj[h][0], acc, 0, 0, 0);
        acc = __builtin_amdgcn_mfma_f32_16x16x32_bf16(F[3], Baj[h][1], acc, 0, 0, 0);
        acc = __builtin_amdgcn_mfma_f32_16x16x32_bf16(F[4], Bae[h][0], acc, 0, 0, 0);
        acc = __builtin_amdgcn_mfma_f32_16x16x32_bf16(F[5], Bae[h][1], acc, 0, 0, 0);
        uint2 p;
        p.x = pack2(silu_f(acc[0] + bb[0]), silu_f(acc[1] + bb[1]));
        p.y = pack2(silu_f(acc[2] + bb[2]), silu_f(acc[3] + bb[3]));
        *(uint2*)(my + (((h * 16 + l15) * LSTR + mt * 8 + 2 * q) << 2)) = p;
      }
    }

    // ---- msg = h1 @ mg_w2 + b
    f32x4 msg[2][4];
    {
      short8 Bh[2][4];
#pragma unroll
      for (int h = 0; h < 2; ++h)
#pragma unroll
        for (int kt = 0; kt < 4; ++kt)
          Bh[h][kt] = *(const short8*)(my + (((h * 16 + l15) * LSTR + 16 * kt + 4 * q) << 2));
#pragma unroll
      for (int mt = 0; mt < 4; ++mt) {
        short8 F[4];
#pragma unroll
        for (int ks = 0; ks < 4; ++ks)
          F[ks] = *(const short8*)(WF + (size_t)(56 + mt * 4 + ks) * 512 + lane * 8);
        f32x4 bb = *(const f32x4*)(mg_b2 + mt * 16 + 4 * q);
#pragma unroll
        for (int h = 0; h < 2; ++h) {
          f32x4 acc = {0.f, 0.f, 0.f, 0.f};
#pragma unroll
          for (int ks = 0; ks < 4; ++ks)
            acc = __builtin_amdgcn_mfma_f32_16x16x32_bf16(F[ks], Bh[h][ks], acc, 0, 0, 0);
          acc[0] += bb[0]; acc[1] += bb[1]; acc[2] += bb[2]; acc[3] += bb[3];
          msg[h][mt] = acc;
        }
      }
    }

    // ---- coeff (reduce over quads), v_agg scatter (atomic; small)
    float part[2] = {0.f, 0.f};
#pragma unroll
    for (int mt = 0; mt < 4; ++mt) {
      f32x4 pw4 = *(const f32x4*)(pe_w + mt * 16 + 4 * q);
#pragma unroll
      for (int h = 0; h < 2; ++h)
        part[h] += msg[h][mt][0] * pw4[0] + msg[h][mt][1] * pw4[1] +
                   msg[h][mt][2] * pw4[2] + msg[h][mt][3] * pw4[3];
    }
    float peb = pe_b[0];
#pragma unroll
    for (int h = 0; h < 2; ++h) {
      part[h] += __shfl_xor(part[h], 16, 64);
      part[h] += __shfl_xor(part[h], 32, 64);
      if (q < 3 && act[h]) {
        float uc = (q == 0) ? uu0[h] : ((q == 1) ? uu1[h] : uu2[h]);
        atomicAdd(&v_agg[(size_t)rown[h] * 3 + q], uc * (part[h] + peb));
      }
    }

    // ---- msg f32 -> LDS (overwrite fdw 0..63)
#pragma unroll
    for (int h = 0; h < 2; ++h)
#pragma unroll
      for (int mt = 0; mt < 4; ++mt)
        *(f32x4*)(my + (((h * 16 + l15) * LSTR + mt * 16 + 4 * q) << 2)) = msg[h][mt];

    // ---- owner aggregation: rows monotone across sorted slots; flush with
    // PLAIN STORE on row change (exclusive ownership, s_agg pre-zeroed).
    for (int e2 = 0; e2 < cntA; ++e2) {
      int rv = __builtin_amdgcn_readlane((e2 & 16) ? rown[1] : rown[0], e2 & 15);
      float val = *(const float*)(my + ((e2 * LSTR + lane) << 2));
      if (rv != prevRow) {
        if (prevRow >= 0) s_agg[(size_t)prevRow * D + lane] = accR;
        prevRow = rv;
        accR = 0.f;
      }
      accR += val;
    }
  }
  if (prevRow >= 0) s_agg[(size_t)prevRow * D + lane] = accR;
}

// ---------------------------------------------------------------------------
// node_out: s_new = s + silu(s_agg)@up_w + up_b ; LayerNorm ; v normalize.
// ---------------------------------------------------------------------------
__global__ __launch_bounds__(256, 4) void node_out(
    const float* __restrict__ s, const float* __restrict__ v,
    const float* __restrict__ up_b,
    const float* __restrict__ ln_g, const float* __restrict__ ln_b,
    const float* __restrict__ s_agg, const float* __restrict__ v_agg,
    const unsigned short* __restrict__ WF, float* __restrict__ out) {
  __shared__ __align__(16) char sm[4 * 8704];
  int tid = threadIdx.x, w = tid >> 6, lane = tid & 63;
  int l15 = lane & 15, q = lane >> 4, fb = q * 8;
  char* my = sm + w * 8704;
  int nb = (blockIdx.x * 4 + w) * 32;
  if (nb >= NN) return;

  short8 Bg[2][2];
#pragma unroll
  for (int h = 0; h < 2; ++h)
#pragma unroll
    for (int kt = 0; kt < 2; ++kt) {
      int n = nb + h * 16 + l15; if (n >= NN) n = NN - 1;
      f32x4 g0 = *(const f32x4*)(s_agg + (size_t)n * D + kt * 32 + fb);
      f32x4 g1 = *(const f32x4*)(s_agg + (size_t)n * D + kt * 32 + fb + 4);
#pragma unroll
      for (int c2 = 0; c2 < 4; ++c2) { g0[c2] = silu_f(g0[c2]); g1[c2] = silu_f(g1[c2]); }
      Bg[h][kt] = pack_frag(g0, g1);
    }
  short8 F[4][2]; f32x4 bb[4];
#pragma unroll
  for (int mt = 0; mt < 4; ++mt) {
    F[mt][0] = *(const short8*)(WF + (size_t)(80 + mt * 2 + 0) * 512 + lane * 8);
    F[mt][1] = *(const short8*)(WF + (size_t)(80 + mt * 2 + 1) * 512 + lane * 8);
    bb[mt] = *(const f32x4*)(up_b + mt * 16 + 4 * q);
  }
  f32x4 sn[2][4];
#pragma unroll
  for (int h = 0; h < 2; ++h) {
    int n = nb + h * 16 + l15; if (n >= NN) n = NN - 1;
#pragma unroll
    for (int mt = 0; mt < 4; ++mt) {
      f32x4 acc = {0.f, 0.f, 0.f, 0.f};
      acc = __builtin_amdgcn_mfma_f32_16x16x32_bf16(F[mt][0], Bg[h][0], acc, 0, 0, 0);
      acc = __builtin_amdgcn_mfma_f32_16x16x32_bf16(F[mt][1], Bg[h][1], acc, 0, 0, 0);
      f32x4 sv = *(const f32x4*)(s + (size_t)n * D + mt * 16 + 4 * q);
      sn[h][mt][0] = acc[0] + bb[mt][0] + sv[0];
      sn[h][mt][1] = acc[1] + bb[mt][1] + sv[1];
      sn[h][mt][2] = acc[2] + bb[mt][2] + sv[2];
      sn[h][mt][3] = acc[3] + bb[mt][3] + sv[3];
    }
  }
  // LayerNorm per node (reduce over quads: lanes q=0..3 share l15)
#pragma unroll
  for (int h = 0; h < 2; ++h) {
    float m = 0.f;
#pragma unroll
    for (int mt = 0; mt < 4; ++mt)
      m += sn[h][mt][0] + sn[h][mt][1] + sn[h][mt][2] + sn[h][mt][3];
    m += __shfl_xor(m, 16, 64);
    m += __shfl_xor(m, 32, 64);
    float mu = m * (1.f / 64.f);
    float vv = 0.f;
#pragma unroll
    for (int mt = 0; mt < 4; ++mt)
#pragma unroll
      for (int r = 0; r < 4; ++r) {
        float d = sn[h][mt][r] - mu;
        vv += d * d;
      }
    vv += __shfl_xor(vv, 16, 64);
    vv += __shfl_xor(vv, 32, 64);
    float inv = 1.f / sqrtf(vv * (1.f / 64.f) + 1e-5f);
#pragma unroll
    for (int mt = 0; mt < 4; ++mt) {
      f32x4 lg = *(const f32x4*)(ln_g + mt * 16 + 4 * q);
      f32x4 lb = *(const f32x4*)(ln_b + mt * 16 + 4 * q);
      f32x4 ov;
#pragma unroll
      for (int r = 0; r < 4; ++r) ov[r] = (sn[h][mt][r] - mu) * inv * lg[r] + lb[r];
      *(f32x4*)(my + (((h * 16 + l15) * 68 + mt * 16 + 4 * q) << 2)) = ov;
    }
  }
#pragma unroll
  for (int h = 0; h < 2; ++h)
#pragma unroll
    for (int e = 0; e < 16; ++e) {
      int n = nb + h * 16 + e;
      if (n < NN) {
        float val = *(const float*)(my + (((h * 16 + e) * 68 + lane) << 2));
        out[(size_t)n * D + lane] = val;
      }
    }
  // v path: lanes q<3 handle component q of node (h, l15)
#pragma unroll
  for (int h = 0; h < 2; ++h) {
    int n = nb + h * 16 + l15;
    if (q < 3 && n < NN) {
      float v0 = v[n * 3 + 0] + v_agg[(size_t)n * 3 + 0];
      float v1 = v[n * 3 + 1] + v_agg[(size_t)n * 3 + 1];
      float v2 = v[n * 3 + 2] + v_agg[(size_t)n * 3 + 2];
      float nrm = sqrtf(v0 * v0 + v1 * v1 + v2 * v2);
      float denom = fmaxf(nrm, 1e-6f);
      float val = (q == 0) ? v0 : ((q == 1) ? v1 : v2);
      out[(size_t)NN * D + (size_t)n * 3 + q] = val / denom;
    }
  }
}

// ---------------------------------------------------------------------------
extern "C" void kernel_launch(void* const* d_in, const int* in_sizes, int n_in,
                              void* d_out, int out_size, void* d_ws, size_t ws_size,
                              hipStream_t stream) {
  const float* s         = (const float*)d_in[0];
  const float* v         = (const float*)d_in[1];
  const int*   ei        = (const int*)d_in[2];
  const float* edge_attr = (const float*)d_in[3];
  const float* evu       = (const float*)d_in[4];
  const float* ng_w1     = (const float*)d_in[5];
  const float* ng_b1     = (const float*)d_in[6];
  const float* ng_w2     = (const float*)d_in[7];
  const float* ng_b2     = (const float*)d_in[8];
  const float* eg_w1     = (const float*)d_in[9];
  const float* eg_b1     = (const float*)d_in[10];
  const float* eg_w2     = (const float*)d_in[11];
  const float* eg_b2     = (const float*)d_in[12];
  const float* mg_w1     = (const float*)d_in[13];
  const float* mg_b1     = (const float*)d_in[14];
  const float* mg_w2     = (const float*)d_in[15];
  const float* mg_b2     = (const float*)d_in[16];
  const float* pe_w      = (const float*)d_in[17];
  const float* pe_b      = (const float*)d_in[18];
  const float* up_w      = (const float*)d_in[19];
  const float* up_b      = (const float*)d_in[20];
  const float* ln_g      = (const float*)d_in[21];
  const float* ln_b      = (const float*)d_in[22];
  (void)in_sizes; (void)n_in; (void)out_size; (void)ws_size;

  float* out = (float*)d_out;
  char* ws = (char*)d_ws;
  size_t o = 0;
  auto carve = [&](size_t bytes) {
    char* p = ws + o;
    o = (o + bytes + 255) & ~(size_t)255;
    return p;
  };
  float* s_agg       = (float*)carve((size_t)NN * D * 4);
  float* v_agg       = (float*)carve((size_t)NN * 3 * 4);
  unsigned short* WF = (unsigned short*)carve((size_t)88 * 512 * 2);
  float* bprime      = (float*)carve((size_t)128 * 4);
  int* cnt           = (int*)carve((size_t)NN * 4);
  int* cursor        = (int*)carve((size_t)NN * 4);
  int* row_start     = (int*)carve((size_t)(NN + 1) * 4);
  int* perm          = (int*)carve((size_t)NE * 4);
  int* rowS          = (int*)carve((size_t)NE * 4);
  int* colS          = (int*)carve((size_t)NE * 4);
  float* evuS        = (float*)carve((size_t)NE * 3 * 4);

  float* h_ng = out;  // d_out[0..NN*64) as scratch; node_out overwrites later

  hipMemsetAsync(cnt, 0, (size_t)NN * 4, stream);

  // prep (frags + inline fold + bprime) fused with the row histogram
  prep_all<<<(NE + 255) / 256, 256, 0, stream>>>(
      eg_w1, mg_w2, ng_w1, up_w, ng_w2, eg_w2, mg_w1, mg_b1, ng_b2, eg_b2,
      ei, WF, bprime, cnt);

  scan_k<<<1, 1024, 0, stream>>>(cnt, row_start, cursor);

  int node_blocks = (NN + 127) / 128;  // 391
  node_pre<<<node_blocks, 256, 0, stream>>>(
      s, ng_b1, WF, h_ng, s_agg, v_agg,
      ei, evu, cursor, perm, rowS, colS, evuS);

  int edge_blocks = (NN / RPW + 3) / 4;  // 1563
  edge_mfma<<<edge_blocks, 256, 0, stream>>>(
      v, edge_attr,
      ng_w1, eg_w1, eg_b1, bprime, mg_b2,
      pe_w, pe_b, h_ng, WF,
      perm, rowS, colS, evuS, row_start,
      s_agg, v_agg);

  node_out<<<node_blocks, 256, 0, stream>>>(
      s, v, up_b, ln_g, ln_b, s_agg, v_agg, WF, out);
}

// Round 7
// 571.043 us; speedup vs baseline: 2.1507x; 2.1507x over previous
//
#include <hip/hip_runtime.h>
#include <math.h>

#define NN 50000
#define NE 800000
#define D 64

typedef __attribute__((ext_vector_type(8))) short short8;
typedef __attribute__((ext_vector_type(4))) float f32x4;

__device__ __forceinline__ float silu_f(float x) { return x / (1.0f + __expf(-x)); }

// v_cvt_pk_bf16_f32: D[15:0]=bf16(S0), D[31:16]=bf16(S1), round-to-nearest-even.
__device__ __forceinline__ unsigned int pack2(float a, float b) {
  unsigned int r;
  asm("v_cvt_pk_bf16_f32 %0, %1, %2" : "=v"(r) : "v"(a), "v"(b));
  return r;
}
__device__ __forceinline__ short8 pack_frag(f32x4 a, f32x4 b) {
  union { unsigned int u[4]; short8 s; } r;
  r.u[0] = pack2(a[0], a[1]);
  r.u[1] = pack2(a[2], a[3]);
  r.u[2] = pack2(b[0], b[1]);
  r.u[3] = pack2(b[2], b[3]);
  return r.s;
}

// ---------------------------------------------------------------------------
// prep_all (fused): weight frags with INLINE fold + bprime. One dispatch.
//   Fold: Wi=ng_w2@mg_w1[0:64], Wj=ng_w2@mg_w1[64:128], We=eg_w2@mg_w1[128:192]
//   b' = mg_b1 + ng_b2@(mg_w1[0:64]+mg_w1[64:128]) + eg_b2@mg_w1[128:192]
// Frag layout (88): 0..7 eg_w1 | 8..55 H1W fold | 56..71 mg_w2 |
//                   72..79 ng_w1[0:64] | 80..87 up_w
// frag elem(L,j) = W[ks*32+(L>>4)*8+j][nt*16+(L&15)]
// ---------------------------------------------------------------------------
__global__ void prep_all(const float* __restrict__ eg_w1,
                         const float* __restrict__ mg_w2,
                         const float* __restrict__ ng_w1,
                         const float* __restrict__ up_w,
                         const float* __restrict__ ng_w2,
                         const float* __restrict__ eg_w2,
                         const float* __restrict__ mg_w1,
                         const float* __restrict__ mg_b1,
                         const float* __restrict__ ng_b2,
                         const float* __restrict__ eg_b2,
                         unsigned short* __restrict__ outWF,
                         float* __restrict__ bprime) {
  int t = blockIdx.x * 256 + threadIdx.x;
  if (t < 88 * 64) {
    int frag = t >> 6, L = t & 63;
    unsigned int p[4];
    if (frag >= 8 && frag < 56) {
      // folded H1W: Wsrc = A_src @ mg_w1[src*64 : src*64+64], inline.
      int lf = frag - 8, mt = lf / 6, s2 = lf % 6, src = s2 >> 1, ks = s2 & 1;
      const float* A = (src == 2) ? eg_w2 : ng_w2;
      const float* M = mg_w1 + (size_t)src * 64 * 128;
      int kb = ks * 32 + (L >> 4) * 8;
      int nc = mt * 16 + (L & 15);
#pragma unroll
      for (int jj = 0; jj < 4; ++jj) {
        float a = 0.f, b = 0.f;
        for (int n = 0; n < 64; ++n) {
          float m = M[(size_t)n * 128 + nc];
          a += A[(kb + 2 * jj) * 64 + n] * m;
          b += A[(kb + 2 * jj + 1) * 64 + n] * m;
        }
        p[jj] = pack2(a, b);
      }
    } else {
      const float* W; int N, nt, ks;
      if (frag < 8)       { W = eg_w1; N = 64; nt = frag >> 1; ks = frag & 1; }
      else if (frag < 72) { int lf = frag - 56; W = mg_w2; N = 64; nt = lf >> 2; ks = lf & 3; }
      else if (frag < 80) { int lf = frag - 72; W = ng_w1; N = 64; nt = lf >> 1; ks = lf & 1; }
      else                { int lf = frag - 80; W = up_w;  N = 64; nt = lf >> 1; ks = lf & 1; }
      int kb = ks * 32 + (L >> 4) * 8;
      int nc = nt * 16 + (L & 15);
#pragma unroll
      for (int jj = 0; jj < 4; ++jj) {
        float a = W[(size_t)(kb + 2 * jj) * N + nc];
        float b = W[(size_t)(kb + 2 * jj + 1) * N + nc];
        p[jj] = pack2(a, b);
      }
    }
    *(uint4*)(outWF + (size_t)frag * 512 + L * 8) = make_uint4(p[0], p[1], p[2], p[3]);
  } else if (t < 88 * 64 + 128) {
    int m = t - 88 * 64;
    float acc = mg_b1[m];
    for (int n = 0; n < 64; ++n)
      acc += ng_b2[n] * (mg_w1[(size_t)n * 128 + m] + mg_w1[(size_t)(64 + n) * 128 + m]) +
             eg_b2[n] * mg_w1[(size_t)(128 + n) * 128 + m];
    bprime[m] = acc;
  }
}

// ---------------------------------------------------------------------------
// node_pre: h_ng = s @ ng_w1[0:64] + b1, MFMA, 32 nodes/wave, barrier-free.
// Also zeroes this wave's rows of s_agg / v_agg (no separate memset dispatch).
// ---------------------------------------------------------------------------
__global__ __launch_bounds__(256, 4) void node_pre(
    const float* __restrict__ s, const float* __restrict__ ng_b1,
    const unsigned short* __restrict__ WF, float* __restrict__ h_ng,
    float* __restrict__ s_agg, float* __restrict__ v_agg) {
  __shared__ __align__(16) char sm[4 * 8704];
  int tid = threadIdx.x, w = tid >> 6, lane = tid & 63;
  int l15 = lane & 15, q = lane >> 4, fb = q * 8;
  char* my = sm + w * 8704;
  int nb = (blockIdx.x * 4 + w) * 32;
  if (nb >= NN) return;

  short8 Bs[2][2];
#pragma unroll
  for (int h = 0; h < 2; ++h)
#pragma unroll
    for (int kt = 0; kt < 2; ++kt) {
      int n = nb + h * 16 + l15; if (n >= NN) n = NN - 1;
      f32x4 x0 = *(const f32x4*)(s + (size_t)n * D + kt * 32 + fb);
      f32x4 x1 = *(const f32x4*)(s + (size_t)n * D + kt * 32 + fb + 4);
      Bs[h][kt] = pack_frag(x0, x1);
    }
  short8 F[4][2]; f32x4 bb[4];
#pragma unroll
  for (int mt = 0; mt < 4; ++mt) {
    F[mt][0] = *(const short8*)(WF + (size_t)(72 + mt * 2 + 0) * 512 + lane * 8);
    F[mt][1] = *(const short8*)(WF + (size_t)(72 + mt * 2 + 1) * 512 + lane * 8);
    bb[mt] = *(const f32x4*)(ng_b1 + mt * 16 + 4 * q);
  }
#pragma unroll
  for (int h = 0; h < 2; ++h)
#pragma unroll
    for (int mt = 0; mt < 4; ++mt) {
      f32x4 acc = {0.f, 0.f, 0.f, 0.f};
      acc = __builtin_amdgcn_mfma_f32_16x16x32_bf16(F[mt][0], Bs[h][0], acc, 0, 0, 0);
      acc = __builtin_amdgcn_mfma_f32_16x16x32_bf16(F[mt][1], Bs[h][1], acc, 0, 0, 0);
      acc[0] += bb[mt][0]; acc[1] += bb[mt][1]; acc[2] += bb[mt][2]; acc[3] += bb[mt][3];
      *(f32x4*)(my + (((h * 16 + l15) * 68 + mt * 16 + 4 * q) << 2)) = acc;
    }
#pragma unroll
  for (int h = 0; h < 2; ++h)
#pragma unroll
    for (int e = 0; e < 16; ++e) {
      int n = nb + h * 16 + e;
      if (n < NN) {
        float val = *(const float*)(my + (((h * 16 + e) * 68 + lane) << 2));
        h_ng[(size_t)n * D + lane] = val;
        s_agg[(size_t)n * D + lane] = 0.f;
      }
    }
#pragma unroll
  for (int h = 0; h < 2; ++h) {
    int n = nb + h * 16 + l15;
    if (q < 3 && n < NN) v_agg[(size_t)n * 3 + q] = 0.f;
  }
}

// ---------------------------------------------------------------------------
// edge_mfma: folded pipeline, UNSORTED edge order (streaming edge_attr/ei/evu),
// 32 edges/wave, zero __syncthreads, direct atomic s_agg scatter.
// Evidence (R1/R2/R4): edge bytes (and time) grow with concurrency -- the
// scatter/gather mix thrashes L2 as reuse distance grows. So LDS is padded
// to 48KB/block to pin occupancy at 3 blocks/CU (R1's config, 534MB/312us),
// while keeping the R4 fold (-48 MFMA, -2 LDS round-trips per wave).
// LSTR=68: row stride mod 32 = 4 banks (conflict-minimal).
// ---------------------------------------------------------------------------
#define LSTR 68
#define LDSW (32 * LSTR * 4)

__global__ __launch_bounds__(256, 3) void edge_mfma(
    const float* __restrict__ v, const int* __restrict__ ei,
    const float* __restrict__ edge_attr, const float* __restrict__ evu,
    const float* __restrict__ ng_w1, const float* __restrict__ eg_w1,
    const float* __restrict__ eg_b1, const float* __restrict__ bprime,
    const float* __restrict__ mg_b2,
    const float* __restrict__ pe_w, const float* __restrict__ pe_b,
    const float* __restrict__ h_ng,
    const unsigned short* __restrict__ WF,
    float* __restrict__ s_agg, float* __restrict__ v_agg) {
  // 48KB (padded past the 34.8KB used) -> exactly 3 blocks/CU.
  __shared__ __align__(16) char sm[49152];
  int tid = threadIdx.x, w = tid >> 6, lane = tid & 63;
  int l15 = lane & 15, q = lane >> 4, fb = q * 8;
  char* my = sm + w * LDSW;
  int eb = (blockIdx.x * 4 + w) * 32;

  // ---- per-edge scalars (redundant across quads; lane's edge = eb+h*16+l15)
  int rown[2], coln[2];
  float rij[2], rji[2], uu0[2], uu1[2], uu2[2], cmag[2];
#pragma unroll
  for (int h = 0; h < 2; ++h) {
    int e = eb + h * 16 + l15;
    int r = ei[e], c = ei[NE + e];
    rown[h] = r; coln[h] = c;
    float u0 = evu[e * 3 + 0], u1 = evu[e * 3 + 1], u2 = evu[e * 3 + 2];
    uu0[h] = u0; uu1[h] = u1; uu2[h] = u2;
    float vi0 = v[r * 3 + 0], vi1 = v[r * 3 + 1], vi2 = v[r * 3 + 2];
    float vj0 = v[c * 3 + 0], vj1 = v[c * 3 + 1], vj2 = v[c * 3 + 2];
    rij[h] = 1.f - (vi0 * u0 + vi1 * u1 + vi2 * u2);
    rji[h] = 1.f + (vj0 * u0 + vj1 * u1 + vj2 * u2);
    float cx = vi1 * vj2 - vi2 * vj1;
    float cy = vi2 * vj0 - vi0 * vj2;
    float cz = vi0 * vj1 - vi1 * vj0;
    cmag[h] = sqrtf(cx * cx + cy * cy + cz * cz);
  }

  // ---- stage B-frags: a_i, a_j (silu of hoisted layer + res*w1last), Xe
  short8 Bai[2][2], Baj[2][2], Bxe[2][2];
  f32x4 w1l[2][2];
#pragma unroll
  for (int kt = 0; kt < 2; ++kt) {
    w1l[kt][0] = *(const f32x4*)(ng_w1 + 64 * 64 + kt * 32 + fb);
    w1l[kt][1] = *(const f32x4*)(ng_w1 + 64 * 64 + kt * 32 + fb + 4);
  }
#pragma unroll
  for (int h = 0; h < 2; ++h)
#pragma unroll
    for (int kt = 0; kt < 2; ++kt) {
      const float* pr = h_ng + (size_t)rown[h] * D + kt * 32 + fb;
      const float* pc = h_ng + (size_t)coln[h] * D + kt * 32 + fb;
      const float* px = edge_attr + (size_t)(eb + h * 16 + l15) * D + kt * 32 + fb;
      f32x4 a0 = *(const f32x4*)pr, a1 = *(const f32x4*)(pr + 4);
      f32x4 b0 = *(const f32x4*)pc, b1 = *(const f32x4*)(pc + 4);
      f32x4 x0 = *(const f32x4*)px, x1 = *(const f32x4*)(px + 4);
      f32x4 si0, si1, sj0, sj1;
#pragma unroll
      for (int c2 = 0; c2 < 4; ++c2) {
        si0[c2] = silu_f(a0[c2] + rij[h] * w1l[kt][0][c2]);
        si1[c2] = silu_f(a1[c2] + rij[h] * w1l[kt][1][c2]);
        sj0[c2] = silu_f(b0[c2] + rji[h] * w1l[kt][0][c2]);
        sj1[c2] = silu_f(b1[c2] + rji[h] * w1l[kt][1][c2]);
      }
      Bai[h][kt] = pack_frag(si0, si1);
      Baj[h][kt] = pack_frag(sj0, sj1);
      Bxe[h][kt] = pack_frag(x0, x1);
    }

  // ---- ae = silu(Xe @ eg_w1 + b + cmag*w_last)  -> LDS fdw 0..31
  {
    short8 F[4][2]; f32x4 bb[4], el[4];
#pragma unroll
    for (int mt = 0; mt < 4; ++mt) {
      F[mt][0] = *(const short8*)(WF + (size_t)(0 + mt * 2 + 0) * 512 + lane * 8);
      F[mt][1] = *(const short8*)(WF + (size_t)(0 + mt * 2 + 1) * 512 + lane * 8);
      bb[mt] = *(const f32x4*)(eg_b1 + mt * 16 + 4 * q);
      el[mt] = *(const f32x4*)(eg_w1 + 64 * 64 + mt * 16 + 4 * q);
    }
#pragma unroll
    for (int h = 0; h < 2; ++h)
#pragma unroll
      for (int mt = 0; mt < 4; ++mt) {
        f32x4 acc = {0.f, 0.f, 0.f, 0.f};
        acc = __builtin_amdgcn_mfma_f32_16x16x32_bf16(F[mt][0], Bxe[h][0], acc, 0, 0, 0);
        acc = __builtin_amdgcn_mfma_f32_16x16x32_bf16(F[mt][1], Bxe[h][1], acc, 0, 0, 0);
        float t0 = silu_f(acc[0] + bb[mt][0] + cmag[h] * el[mt][0]);
        float t1 = silu_f(acc[1] + bb[mt][1] + cmag[h] * el[mt][1]);
        float t2 = silu_f(acc[2] + bb[mt][2] + cmag[h] * el[mt][2]);
        float t3 = silu_f(acc[3] + bb[mt][3] + cmag[h] * el[mt][3]);
        uint2 p; p.x = pack2(t0, t1); p.y = pack2(t2, t3);
        *(uint2*)(my + (((h * 16 + l15) * LSTR + mt * 8 + 2 * q) << 2)) = p;
      }
  }

  // ---- read ae B-frags into regs (before h1 overwrites fdw 0..31)
  short8 Bae[2][2];
#pragma unroll
  for (int h = 0; h < 2; ++h)
#pragma unroll
    for (int kt = 0; kt < 2; ++kt)
      Bae[h][kt] = *(const short8*)(my + (((h * 16 + l15) * LSTR + 16 * kt + 4 * q) << 2));

  // ---- h1 = silu(ai@Wi + aj@Wj + ae@We + b'): write fdw 0..63
#pragma unroll
  for (int mt = 0; mt < 8; ++mt) {
    short8 F[6];
#pragma unroll
    for (int s2 = 0; s2 < 6; ++s2)
      F[s2] = *(const short8*)(WF + (size_t)(8 + mt * 6 + s2) * 512 + lane * 8);
    f32x4 bb = *(const f32x4*)(bprime + mt * 16 + 4 * q);
#pragma unroll
    for (int h = 0; h < 2; ++h) {
      f32x4 acc = {0.f, 0.f, 0.f, 0.f};
      acc = __builtin_amdgcn_mfma_f32_16x16x32_bf16(F[0], Bai[h][0], acc, 0, 0, 0);
      acc = __builtin_amdgcn_mfma_f32_16x16x32_bf16(F[1], Bai[h][1], acc, 0, 0, 0);
      acc = __builtin_amdgcn_mfma_f32_16x16x32_bf16(F[2], Baj[h][0], acc, 0, 0, 0);
      acc = __builtin_amdgcn_mfma_f32_16x16x32_bf16(F[3], Baj[h][1], acc, 0, 0, 0);
      acc = __builtin_amdgcn_mfma_f32_16x16x32_bf16(F[4], Bae[h][0], acc, 0, 0, 0);
      acc = __builtin_amdgcn_mfma_f32_16x16x32_bf16(F[5], Bae[h][1], acc, 0, 0, 0);
      uint2 p;
      p.x = pack2(silu_f(acc[0] + bb[0]), silu_f(acc[1] + bb[1]));
      p.y = pack2(silu_f(acc[2] + bb[2]), silu_f(acc[3] + bb[3]));
      *(uint2*)(my + (((h * 16 + l15) * LSTR + mt * 8 + 2 * q) << 2)) = p;
    }
  }

  // ---- msg = h1 @ mg_w2 + b  (read 4 k-tiles)
  f32x4 msg[2][4];
  {
    short8 Bh[2][4];
#pragma unroll
    for (int h = 0; h < 2; ++h)
#pragma unroll
      for (int kt = 0; kt < 4; ++kt)
        Bh[h][kt] = *(const short8*)(my + (((h * 16 + l15) * LSTR + 16 * kt + 4 * q) << 2));
#pragma unroll
    for (int mt = 0; mt < 4; ++mt) {
      short8 F[4];
#pragma unroll
      for (int ks = 0; ks < 4; ++ks)
        F[ks] = *(const short8*)(WF + (size_t)(56 + mt * 4 + ks) * 512 + lane * 8);
      f32x4 bb = *(const f32x4*)(mg_b2 + mt * 16 + 4 * q);
#pragma unroll
      for (int h = 0; h < 2; ++h) {
        f32x4 acc = {0.f, 0.f, 0.f, 0.f};
#pragma unroll
        for (int ks = 0; ks < 4; ++ks)
          acc = __builtin_amdgcn_mfma_f32_16x16x32_bf16(F[ks], Bh[h][ks], acc, 0, 0, 0);
        acc[0] += bb[0]; acc[1] += bb[1]; acc[2] += bb[2]; acc[3] += bb[3];
        msg[h][mt] = acc;
      }
    }
  }

  // ---- coeff (reduce over quads), v_agg scatter
  float part[2] = {0.f, 0.f};
#pragma unroll
  for (int mt = 0; mt < 4; ++mt) {
    f32x4 pw4 = *(const f32x4*)(pe_w + mt * 16 + 4 * q);
#pragma unroll
    for (int h = 0; h < 2; ++h)
      part[h] += msg[h][mt][0] * pw4[0] + msg[h][mt][1] * pw4[1] +
                 msg[h][mt][2] * pw4[2] + msg[h][mt][3] * pw4[3];
  }
  float peb = pe_b[0];
#pragma unroll
  for (int h = 0; h < 2; ++h) {
    part[h] += __shfl_xor(part[h], 16, 64);
    part[h] += __shfl_xor(part[h], 32, 64);
    if (q < 3) {
      float uc = (q == 0) ? uu0[h] : ((q == 1) ? uu1[h] : uu2[h]);
      atomicAdd(&v_agg[(size_t)rown[h] * 3 + q], uc * (part[h] + peb));
    }
  }

  // ---- msg f32 -> LDS (overwrite fdw 0..63), coalesced atomic scatter
#pragma unroll
  for (int h = 0; h < 2; ++h)
#pragma unroll
    for (int mt = 0; mt < 4; ++mt)
      *(f32x4*)(my + (((h * 16 + l15) * LSTR + mt * 16 + 4 * q) << 2)) = msg[h][mt];
#pragma unroll
  for (int h = 0; h < 2; ++h)
#pragma unroll
    for (int e = 0; e < 16; ++e) {
      int sr = __builtin_amdgcn_readlane(rown[h], e);
      float val = *(const float*)(my + (((h * 16 + e) * LSTR + lane) << 2));
      atomicAdd(&s_agg[(size_t)sr * D + lane], val);
    }
}

// ---------------------------------------------------------------------------
// node_out: s_new = s + silu(s_agg)@up_w + up_b ; LayerNorm ; v normalize.
// ---------------------------------------------------------------------------
__global__ __launch_bounds__(256, 4) void node_out(
    const float* __restrict__ s, const float* __restrict__ v,
    const float* __restrict__ up_b,
    const float* __restrict__ ln_g, const float* __restrict__ ln_b,
    const float* __restrict__ s_agg, const float* __restrict__ v_agg,
    const unsigned short* __restrict__ WF, float* __restrict__ out) {
  __shared__ __align__(16) char sm[4 * 8704];
  int tid = threadIdx.x, w = tid >> 6, lane = tid & 63;
  int l15 = lane & 15, q = lane >> 4, fb = q * 8;
  char* my = sm + w * 8704;
  int nb = (blockIdx.x * 4 + w) * 32;
  if (nb >= NN) return;

  short8 Bg[2][2];
#pragma unroll
  for (int h = 0; h < 2; ++h)
#pragma unroll
    for (int kt = 0; kt < 2; ++kt) {
      int n = nb + h * 16 + l15; if (n >= NN) n = NN - 1;
      f32x4 g0 = *(const f32x4*)(s_agg + (size_t)n * D + kt * 32 + fb);
      f32x4 g1 = *(const f32x4*)(s_agg + (size_t)n * D + kt * 32 + fb + 4);
#pragma unroll
      for (int c2 = 0; c2 < 4; ++c2) { g0[c2] = silu_f(g0[c2]); g1[c2] = silu_f(g1[c2]); }
      Bg[h][kt] = pack_frag(g0, g1);
    }
  short8 F[4][2]; f32x4 bb[4];
#pragma unroll
  for (int mt = 0; mt < 4; ++mt) {
    F[mt][0] = *(const short8*)(WF + (size_t)(80 + mt * 2 + 0) * 512 + lane * 8);
    F[mt][1] = *(const short8*)(WF + (size_t)(80 + mt * 2 + 1) * 512 + lane * 8);
    bb[mt] = *(const f32x4*)(up_b + mt * 16 + 4 * q);
  }
  f32x4 sn[2][4];
#pragma unroll
  for (int h = 0; h < 2; ++h) {
    int n = nb + h * 16 + l15; if (n >= NN) n = NN - 1;
#pragma unroll
    for (int mt = 0; mt < 4; ++mt) {
      f32x4 acc = {0.f, 0.f, 0.f, 0.f};
      acc = __builtin_amdgcn_mfma_f32_16x16x32_bf16(F[mt][0], Bg[h][0], acc, 0, 0, 0);
      acc = __builtin_amdgcn_mfma_f32_16x16x32_bf16(F[mt][1], Bg[h][1], acc, 0, 0, 0);
      f32x4 sv = *(const f32x4*)(s + (size_t)n * D + mt * 16 + 4 * q);
      sn[h][mt][0] = acc[0] + bb[mt][0] + sv[0];
      sn[h][mt][1] = acc[1] + bb[mt][1] + sv[1];
      sn[h][mt][2] = acc[2] + bb[mt][2] + sv[2];
      sn[h][mt][3] = acc[3] + bb[mt][3] + sv[3];
    }
  }
  // LayerNorm per node (reduce over quads: lanes q=0..3 share l15)
#pragma unroll
  for (int h = 0; h < 2; ++h) {
    float m = 0.f;
#pragma unroll
    for (int mt = 0; mt < 4; ++mt)
      m += sn[h][mt][0] + sn[h][mt][1] + sn[h][mt][2] + sn[h][mt][3];
    m += __shfl_xor(m, 16, 64);
    m += __shfl_xor(m, 32, 64);
    float mu = m * (1.f / 64.f);
    float vv = 0.f;
#pragma unroll
    for (int mt = 0; mt < 4; ++mt)
#pragma unroll
      for (int r = 0; r < 4; ++r) {
        float d = sn[h][mt][r] - mu;
        vv += d * d;
      }
    vv += __shfl_xor(vv, 16, 64);
    vv += __shfl_xor(vv, 32, 64);
    float inv = 1.f / sqrtf(vv * (1.f / 64.f) + 1e-5f);
#pragma unroll
    for (int mt = 0; mt < 4; ++mt) {
      f32x4 lg = *(const f32x4*)(ln_g + mt * 16 + 4 * q);
      f32x4 lb = *(const f32x4*)(ln_b + mt * 16 + 4 * q);
      f32x4 ov;
#pragma unroll
      for (int r = 0; r < 4; ++r) ov[r] = (sn[h][mt][r] - mu) * inv * lg[r] + lb[r];
      *(f32x4*)(my + (((h * 16 + l15) * 68 + mt * 16 + 4 * q) << 2)) = ov;
    }
  }
#pragma unroll
  for (int h = 0; h < 2; ++h)
#pragma unroll
    for (int e = 0; e < 16; ++e) {
      int n = nb + h * 16 + e;
      if (n < NN) {
        float val = *(const float*)(my + (((h * 16 + e) * 68 + lane) << 2));
        out[(size_t)n * D + lane] = val;
      }
    }
  // v path: lanes q<3 handle component q of node (h, l15)
#pragma unroll
  for (int h = 0; h < 2; ++h) {
    int n = nb + h * 16 + l15;
    if (q < 3 && n < NN) {
      float v0 = v[n * 3 + 0] + v_agg[(size_t)n * 3 + 0];
      float v1 = v[n * 3 + 1] + v_agg[(size_t)n * 3 + 1];
      float v2 = v[n * 3 + 2] + v_agg[(size_t)n * 3 + 2];
      float nrm = sqrtf(v0 * v0 + v1 * v1 + v2 * v2);
      float denom = fmaxf(nrm, 1e-6f);
      float val = (q == 0) ? v0 : ((q == 1) ? v1 : v2);
      out[(size_t)NN * D + (size_t)n * 3 + q] = val / denom;
    }
  }
}

// ---------------------------------------------------------------------------
extern "C" void kernel_launch(void* const* d_in, const int* in_sizes, int n_in,
                              void* d_out, int out_size, void* d_ws, size_t ws_size,
                              hipStream_t stream) {
  const float* s         = (const float*)d_in[0];
  const float* v         = (const float*)d_in[1];
  const int*   ei        = (const int*)d_in[2];
  const float* edge_attr = (const float*)d_in[3];
  const float* evu       = (const float*)d_in[4];
  const float* ng_w1     = (const float*)d_in[5];
  const float* ng_b1     = (const float*)d_in[6];
  const float* ng_w2     = (const float*)d_in[7];
  const float* ng_b2     = (const float*)d_in[8];
  const float* eg_w1     = (const float*)d_in[9];
  const float* eg_b1     = (const float*)d_in[10];
  const float* eg_w2     = (const float*)d_in[11];
  const float* eg_b2     = (const float*)d_in[12];
  const float* mg_w1     = (const float*)d_in[13];
  const float* mg_b1     = (const float*)d_in[14];
  const float* mg_w2     = (const float*)d_in[15];
  const float* mg_b2     = (const float*)d_in[16];
  const float* pe_w      = (const float*)d_in[17];
  const float* pe_b      = (const float*)d_in[18];
  const float* up_w      = (const float*)d_in[19];
  const float* up_b      = (const float*)d_in[20];
  const float* ln_g      = (const float*)d_in[21];
  const float* ln_b      = (const float*)d_in[22];
  (void)in_sizes; (void)n_in; (void)out_size; (void)ws_size;

  float* out = (float*)d_out;
  char* ws = (char*)d_ws;
  size_t o = 0;
  auto carve = [&](size_t bytes) {
    char* p = ws + o;
    o = (o + bytes + 255) & ~(size_t)255;
    return p;
  };
  float* s_agg       = (float*)carve((size_t)NN * D * 4);
  float* v_agg       = (float*)carve((size_t)NN * 3 * 4);
  unsigned short* WF = (unsigned short*)carve((size_t)88 * 512 * 2);
  float* bprime      = (float*)carve((size_t)128 * 4);

  float* h_ng = out;  // d_out[0..NN*64) as scratch; node_out overwrites later

  // 4 dispatches total (each extra dispatch costs ~50us: R3/R5 evidence).
  prep_all<<<23, 256, 0, stream>>>(
      eg_w1, mg_w2, ng_w1, up_w, ng_w2, eg_w2, mg_w1, mg_b1, ng_b2, eg_b2,
      WF, bprime);

  int node_blocks = (NN + 127) / 128;  // 391
  node_pre<<<node_blocks, 256, 0, stream>>>(s, ng_b1, WF, h_ng, s_agg, v_agg);

  edge_mfma<<<NE / 128, 256, 0, stream>>>(
      v, ei, edge_attr, evu,
      ng_w1, eg_w1, eg_b1, bprime, mg_b2,
      pe_w, pe_b, h_ng, WF, s_agg, v_agg);

  node_out<<<node_blocks, 256, 0, stream>>>(
      s, v, up_b, ln_g, ln_b, s_agg, v_agg, WF, out);
}